// Round 12
// baseline (2181.611 us; speedup 1.0000x reference)
//
#include <hip/hip_runtime.h>
#include <stdint.h>

// E=8, C=1024, H=2048, I=4096.  gate_up = X@Wgu; act = silu(g)*u; out = act@Wd
// Round 12: A removed from LDS entirely.
//  - X and act stored PRE-TILED in MFMA fragment order:
//    [slice=(e*4+bm)*2+wm][t][kk][m][lane]*16B  -> each A-frag load is one
//    coalesced global_load_dwordx4 (L1/L2-resident; 4 wn-waves share).
//  - LDS holds only B: 2 x 32 KB = 64 KiB -> 2 blocks/CU.
//  - B path unchanged from round 11 (loadB8 dwordx4, cvt_pk, b128 writes,
//    swz8 involution, 0 bank conflicts).
//  - 2 phases/tile (kk0/kk1); A regs double-buffered via 2-tile unroll
//    (afP/afQ, static indexing); ONE static vmcnt(8) at phase B (forces
//    bk(t+1)+af1 done, leaves next-kk0 A in flight); barrier needs only
//    lgkmcnt(0) since A never crosses it.

#define E_  8
#define C_  1024
#define H_  2048
#define I_  4096
#define N1_ 8192   // 2*I

typedef __bf16 bf16x8 __attribute__((ext_vector_type(8)));
typedef float  f32x4  __attribute__((ext_vector_type(4)));

__device__ __forceinline__ unsigned short f2bf(float f) {
    union { float f; unsigned u; } v; v.f = f;
    unsigned u = v.u;
    return (unsigned short)((u + 0x7FFFu + ((u >> 16) & 1u)) >> 16);  // RNE
}

__device__ __forceinline__ unsigned swz8(unsigned row) {
    return ((row ^ (row >> 2)) & 7u) << 4;   // 16B-slot XOR constant
}

#define SBAR0 __builtin_amdgcn_sched_barrier(0)
#define MFMA_ __builtin_amdgcn_mfma_f32_16x16x32_bf16

// ---------------- convert X -> pre-tiled bf16 fragment layout ----------------
// dest unit (16B): slice=(e*4+bm)*2+wm (NT=32): off = slice*512KB
//   + ((t*2+kk)*8+m)*1024 + (lr+kgrp*16)*16
// where row=bm*256+wm*128+m*16+lr, kelem = t*64+kk*32+kgrp*8 (+0..7)
__global__ void k_convert_tiled(const float* __restrict__ src,
                                unsigned short* __restrict__ dst) {
    const int NU = E_ * C_ * (H_ / 8);   // 2,097,152 units of 8 elems
    int idx = blockIdx.x * blockDim.x + threadIdx.x;
    int stride = gridDim.x * blockDim.x;
    for (int u = idx; u < NU; u += stride) {
        int k0  = u & 255;            // 8-elem unit along H
        int row = (u >> 8) & 1023;
        int e   = u >> 18;
        const float4* s = reinterpret_cast<const float4*>(
            src + ((size_t)(e * 1024 + row) * H_) + k0 * 8);
        float4 a = s[0], b = s[1];
        ushort4 lo, hi;
        lo.x = f2bf(a.x); lo.y = f2bf(a.y); lo.z = f2bf(a.z); lo.w = f2bf(a.w);
        hi.x = f2bf(b.x); hi.y = f2bf(b.y); hi.z = f2bf(b.z); hi.w = f2bf(b.w);
        int bm = row >> 8, wm = (row >> 7) & 1, m = (row >> 4) & 7, lr = row & 15;
        int t = k0 >> 3, kk = (k0 >> 2) & 1, kgrp = k0 & 3;
        size_t off = (size_t)((e * 4 + bm) * 2 + wm) * (32 * 16384)
                   + (size_t)((t * 2 + kk) * 8 + m) * 1024
                   + (size_t)(lr + kgrp * 16) * 16;
        char* d = (char*)dst + off;
        *reinterpret_cast<ushort4*>(d)     = lo;
        *reinterpret_cast<ushort4*>(d + 8) = hi;
    }
}

// ---------------- B staging (identical to round 11) ----------------
template<int LDB>
__device__ __forceinline__ void loadB8(const char* __restrict__ gcol, int kt,
                                       float4 (&bk)[8]) {
    const char* p = gcol + (size_t)(kt * 64) * LDB;
    #pragma unroll
    for (int i = 0; i < 8; ++i)
        bk[i] = *reinterpret_cast<const float4*>(p + (size_t)i * LDB);
}

__device__ __forceinline__ void cvtWriteB(char* bB, const float4 (&bk)[8],
                                          int rg, int kg8) {
    const float* f = reinterpret_cast<const float*>(&bk[0]);
    #pragma unroll
    for (int j = 0; j < 4; ++j) {
        unsigned u[4];
        #pragma unroll
        for (int p2 = 0; p2 < 4; ++p2) {
            float lo = f[(2 * p2) * 4 + j];
            float hi = f[(2 * p2 + 1) * 4 + j];
            asm("v_cvt_pk_bf16_f32 %0, %1, %2" : "=v"(u[p2]) : "v"(lo), "v"(hi));
        }
        unsigned q = (unsigned)(rg * 4 + j);
        unsigned phys = q * 128 + (((unsigned)kg8 * 16) ^ swz8(q));
        *reinterpret_cast<uint4*>(bB + phys) = make_uint4(u[0], u[1], u[2], u[3]);
    }
}

__device__ __forceinline__ const bf16x8* frag128(const char* tile, int row, int kb) {
    unsigned phys = (unsigned)(row * 128) + ((unsigned)kb ^ swz8((unsigned)row));
    return reinterpret_cast<const bf16x8*>(tile + phys);
}

// ---------------- per-tile body (2 phases, A from global) ----------------
#define TILE_D(T, AFC, AFN) do {                                               \
    const int t_ = (T);                                                        \
    char* Bb = lds + (t_ & 1) * 32768;                                         \
    char* nB = lds + ((t_ + 1) & 1) * 32768;                                   \
    const bool hs1 = (t_ + 1) < NT, hs2 = (t_ + 2) < NT;                       \
    bf16x8 b0[4], bg[4], af1[8];                                               \
    /* phase A (kk0) */                                                        \
    _Pragma("unroll")                                                          \
    for (int n = 0; n < 4; ++n)                                                \
        b0[n] = *frag128(Bb, wn * 64 + n * 16 + r, kg * 16);                   \
    _Pragma("unroll")                                                          \
    for (int m = 0; m < 8; ++m)                                                \
        af1[m] = *reinterpret_cast<const bf16x8*>(                             \
            gAw + (size_t)((t_ * 2 + 1) * 8 + m) * 1024);                      \
    SBAR0;                                                                     \
    asm volatile("s_waitcnt lgkmcnt(0)" ::: "memory");                         \
    SBAR0;                                                                     \
    __builtin_amdgcn_s_setprio(1);                                             \
    _Pragma("unroll")                                                          \
    for (int m = 0; m < 8; ++m)                                                \
        _Pragma("unroll")                                                      \
        for (int n = 0; n < 4; ++n)                                            \
            acc[m][n] = MFMA_(AFC[m], b0[n], acc[m][n], 0, 0, 0);              \
    __builtin_amdgcn_s_setprio(0);                                             \
    SBAR0;                                                                     \
    /* phase B (kk1) */                                                        \
    _Pragma("unroll")                                                          \
    for (int n = 0; n < 4; ++n)                                                \
        bg[n] = *frag128(Bb, wn * 64 + n * 16 + r, 64 + kg * 16);              \
    if (hs1) {                                                                 \
        _Pragma("unroll")                                                      \
        for (int m = 0; m < 8; ++m)                                            \
            AFN[m] = *reinterpret_cast<const bf16x8*>(                         \
                gAw + (size_t)((t_ + 1) * 2 * 8 + m) * 1024);                  \
    }                                                                          \
    SBAR0;                                                                     \
    if (hs1) {                                                                 \
        asm volatile("s_waitcnt vmcnt(8)" ::: "memory");                       \
        SBAR0;                                                                 \
        cvtWriteB(nB, bk, rg, kg8);                                            \
        SBAR0;                                                                 \
        if (hs2) { loadB8<LDB>(gBcol, t_ + 2, bk); SBAR0; }                    \
    }                                                                          \
    asm volatile("s_waitcnt lgkmcnt(0)" ::: "memory");                         \
    SBAR0;                                                                     \
    __builtin_amdgcn_s_setprio(1);                                             \
    _Pragma("unroll")                                                          \
    for (int m = 0; m < 8; ++m)                                                \
        _Pragma("unroll")                                                      \
        for (int n = 0; n < 4; ++n)                                            \
            acc[m][n] = MFMA_(af1[m], bg[n], acc[m][n], 0, 0, 0);              \
    __builtin_amdgcn_s_setprio(0);                                             \
    SBAR0;                                                                     \
    if (hs1) {                                                                 \
        asm volatile("s_waitcnt lgkmcnt(0)" ::: "memory");                     \
        SBAR0;                                                                 \
        __builtin_amdgcn_s_barrier();                                          \
        SBAR0;                                                                 \
    }                                                                          \
} while (0)

// MODE 0: gemm1 (B=Wgu native, gate|up interleave, silu -> act TILED bf16)
// MODE 1: gemm2 (B=Wd native, f32 row-major out)
template<int LDB, int NT, int BMG, int BNG, int MODE>
__global__ __launch_bounds__(512, 2) void k_gemm_d(
    const unsigned short* __restrict__ Atiled,
    const float* __restrict__ B,
    void* __restrict__ Cout,
    size_t sBbytes) {
    __shared__ char lds[65536];   // B only: 2 x 32 KB

    const int tid = threadIdx.x, lane = tid & 63, wave = tid >> 6;
    const int wm = wave >> 2, wn = wave & 3;
    const int kg = lane >> 4, r = lane & 15;
    const int rg = tid & 63, kg8 = tid >> 6;

    unsigned flat = blockIdx.x;
    unsigned cpx = gridDim.x >> 3;
    unsigned nid = (flat & 7u) * cpx + (flat >> 3);
    const int bm = nid % BMG;
    const int bn = (nid / BMG) % BNG;
    const int e  = nid / (BMG * BNG);

    const char* gAw = (const char*)Atiled
                    + (size_t)((e * BMG + bm) * 2 + wm) * ((size_t)NT * 16384)
                    + (size_t)lane * 16;
    size_t colstart;
    if constexpr (MODE == 0)
        colstart = (size_t)(bn * 128 + ((rg >> 4) & 3) * 32 + ((rg >> 2) & 1) * 16
                            + (rg & 3) * 4)
                 + (((rg >> 3) & 1) ? (size_t)I_ : (size_t)0);
    else
        colstart = (size_t)(bn * 256 + rg * 4);
    const char* gBcol = (const char*)B + sBbytes * e + colstart * 4
                      + (size_t)kg8 * 8 * LDB;

    float4 bk[8];
    bf16x8 afP[8], afQ[8];

    // ---------------- prologue ----------------
    loadB8<LDB>(gBcol, 0, bk);
    SBAR0;
    #pragma unroll
    for (int m = 0; m < 8; ++m)
        afP[m] = *reinterpret_cast<const bf16x8*>(gAw + (size_t)m * 1024);
    SBAR0;
    asm volatile("s_waitcnt vmcnt(8)" ::: "memory");   // bk(0) done, afP in flight
    SBAR0;
    cvtWriteB(lds, bk, rg, kg8);
    SBAR0;
    loadB8<LDB>(gBcol, 1, bk);
    SBAR0;
    asm volatile("s_waitcnt lgkmcnt(0)" ::: "memory");
    SBAR0;
    __builtin_amdgcn_s_barrier();
    SBAR0;

    f32x4 acc[8][4] = {};

    for (int tt = 0; tt < NT; tt += 2) {
        TILE_D(tt,     afP, afQ);
        TILE_D(tt + 1, afQ, afP);
    }

    // ---------------- epilogue ----------------
    const int row0 = bm * 256 + wm * 128 + kg * 4;
    if constexpr (MODE == 0) {
        // write act in gemm2's tiled layout (NT2=64 over I)
        char* act = (char*)Cout;
        const int col0 = bn * 128 + wn * 32 + r;
        #pragma unroll
        for (int m = 0; m < 8; ++m)
            #pragma unroll
            for (int n = 0; n < 2; ++n)
                #pragma unroll
                for (int j = 0; j < 4; ++j) {
                    float g = acc[m][n][j], u = acc[m][n + 2][j];
                    float s = g / (1.0f + __expf(-g)) * u;
                    int row = row0 + m * 16 + j;
                    int col = col0 + n * 16;
                    int bm2 = row >> 8, wm2 = (row >> 7) & 1;
                    int m2 = (row >> 4) & 7, lr2 = row & 15;
                    int t2 = col >> 6, kk2 = (col >> 5) & 1, kgrp2 = (col >> 3) & 3;
                    size_t off = (size_t)((e * 4 + bm2) * 2 + wm2) * (64 * 16384)
                               + (size_t)((t2 * 2 + kk2) * 8 + m2) * 1024
                               + (size_t)(lr2 + kgrp2 * 16) * 16
                               + (size_t)(col & 7) * 2;
                    *reinterpret_cast<unsigned short*>(act + off) = f2bf(s);
                }
    } else {
        float* o = (float*)Cout + (size_t)e * C_ * H_;
        const int col0 = bn * 256 + wn * 64 + r;
        #pragma unroll
        for (int m = 0; m < 8; ++m)
            #pragma unroll
            for (int n = 0; n < 4; ++n)
                #pragma unroll
                for (int j = 0; j < 4; ++j)
                    o[(size_t)(row0 + m * 16 + j) * H_ + col0 + n * 16] = acc[m][n][j];
    }
}

// ---------------- launch ----------------
extern "C" void kernel_launch(void* const* d_in, const int* in_sizes, int n_in,
                              void* d_out, int out_size, void* d_ws, size_t ws_size,
                              hipStream_t stream) {
    const float* hs  = (const float*)d_in[0];   // [E][C][H]
    const float* wgu = (const float*)d_in[1];   // [E][H][2I]
    const float* wd  = (const float*)d_in[2];   // [E][I][H]
    float* out = (float*)d_out;

    char* ws = (char*)d_ws;
    unsigned short* Xp   = (unsigned short*)(ws);                 // 33,554,432 B (tiled)
    unsigned short* actT = (unsigned short*)(ws + 33554432ull);   // 67,108,864 B (tiled)

    k_convert_tiled<<<2048, 256, 0, stream>>>(hs, Xp);

    // GEMM1: Xp x Wgu native [H][2I] -> actT (tiled). NT=32, 1024 blocks.
    k_gemm_d<N1_ * 4, H_ / 64, 4, 32, 0><<<dim3(1024), 512, 0, stream>>>(
        Xp, wgu, actT, (size_t)H_ * N1_ * 4);

    // GEMM2: actT x Wd native [I][H] -> out f32 [EC][H]. NT=64, 256 blocks.
    k_gemm_d<H_ * 4, I_ / 64, 4, 8, 1><<<dim3(256), 512, 0, stream>>>(
        actT, wd, out, (size_t)I_ * H_ * 4);
}

// Round 13
// 474.345 us; speedup vs baseline: 4.5992x; 4.5992x over previous
//
#include <hip/hip_runtime.h>
#include <stdint.h>

// E=8, C=1024, H=2048, I=4096.  gate_up = X@Wgu; act = silu(g)*u; out = act@Wd
// Round 13: round-11 fused-B structure; ONE change: all staging relocated to
// the tile TOP (right after the boundary barrier):
//   vmcnt(0); cvtWriteB(nB); stageA(t+1)x4; loadB8(t+2)->bk
// The 4 compute phases contain ONLY ds_reads + lgkmcnt(0) + MFMA — no vmem
// wait ever precedes a mid-tile MFMA (R11 had vmcnt(4)+cvt+load serially
// inside phase 2 for every wave = the 34.5% plateau).
// Boundary wait is exact by FIFO: outstanding = [A x4 oldest, B x8 newest]
// -> vmcnt(8) completes exactly the A-gloads, B(t+2) stays in flight.
// Everything else (swz8 involution, gate|up col interleave, epilogues,
// XCD chunking) identical to round 11.

#define E_  8
#define C_  1024
#define H_  2048
#define I_  4096
#define N1_ 8192   // 2*I

typedef __bf16 bf16x8 __attribute__((ext_vector_type(8)));
typedef float  f32x4  __attribute__((ext_vector_type(4)));

typedef __attribute__((address_space(3))) unsigned       lds_uint;
typedef const __attribute__((address_space(1))) unsigned glob_uint;

__device__ __forceinline__ void gload_lds16(const void* g, void* l) {
    __builtin_amdgcn_global_load_lds((glob_uint*)g, (lds_uint*)l, 16, 0, 0);
}

__device__ __forceinline__ unsigned short f2bf(float f) {
    union { float f; unsigned u; } v; v.f = f;
    unsigned u = v.u;
    return (unsigned short)((u + 0x7FFFu + ((u >> 16) & 1u)) >> 16);  // RNE
}

__device__ __forceinline__ unsigned swz8(unsigned row) {
    return ((row ^ (row >> 2)) & 7u) << 4;   // 16B-slot XOR constant
}

#define SBAR0 __builtin_amdgcn_sched_barrier(0)
#define MFMA_ __builtin_amdgcn_mfma_f32_16x16x32_bf16

// ---------------- elementwise fp32 -> bf16 (X only) ----------------
__global__ void k_convert(const float* __restrict__ src,
                          unsigned short* __restrict__ dst, int n8) {
    int idx = blockIdx.x * blockDim.x + threadIdx.x;
    int stride = gridDim.x * blockDim.x;
    for (int i = idx; i < n8; i += stride) {
        const float4* s = reinterpret_cast<const float4*>(src + (size_t)i * 8);
        float4 a = s[0], b = s[1];
        ushort4 lo, hi;
        lo.x = f2bf(a.x); lo.y = f2bf(a.y); lo.z = f2bf(a.z); lo.w = f2bf(a.w);
        hi.x = f2bf(b.x); hi.y = f2bf(b.y); hi.z = f2bf(b.z); hi.w = f2bf(b.w);
        ushort4* d = reinterpret_cast<ushort4*>(dst + (size_t)i * 8);
        d[0] = lo; d[1] = hi;
    }
}

// ---------------- staging helpers (identical to round 11) ----------------
template<int LD>
__device__ __forceinline__ void stageA(const char* __restrict__ gtile,
                                       char* ldst, int j, int tid, int wave) {
    unsigned p   = (unsigned)(j * 8192 + tid * 16);
    unsigned row = p >> 7;
    unsigned kb  = (p & 127u) ^ swz8(row);
    const char* gp = gtile + (size_t)row * LD + kb;
    void* lp = ldst + j * 8192 + wave * 1024;   // wave-uniform base
    gload_lds16(gp, lp);
}

__device__ __forceinline__ const bf16x8* frag128(const char* tile, int row, int kb) {
    unsigned phys = (unsigned)(row * 128) + ((unsigned)kb ^ swz8((unsigned)row));
    return reinterpret_cast<const bf16x8*>(tile + phys);
}

template<int LDB>
__device__ __forceinline__ void loadB8(const char* __restrict__ gcol, int kt,
                                       float4 (&bk)[8]) {
    const char* p = gcol + (size_t)(kt * 64) * LDB;
    #pragma unroll
    for (int i = 0; i < 8; ++i)
        bk[i] = *reinterpret_cast<const float4*>(p + (size_t)i * LDB);
}

__device__ __forceinline__ void cvtWriteB(char* bB, const float4 (&bk)[8],
                                          int rg, int kg8) {
    const float* f = reinterpret_cast<const float*>(&bk[0]);
    #pragma unroll
    for (int j = 0; j < 4; ++j) {
        unsigned u[4];
        #pragma unroll
        for (int p2 = 0; p2 < 4; ++p2) {
            float lo = f[(2 * p2) * 4 + j];
            float hi = f[(2 * p2 + 1) * 4 + j];
            asm("v_cvt_pk_bf16_f32 %0, %1, %2" : "=v"(u[p2]) : "v"(lo), "v"(hi));
        }
        unsigned q = (unsigned)(rg * 4 + j);
        unsigned phys = q * 128 + (((unsigned)kg8 * 16) ^ swz8(q));
        *reinterpret_cast<uint4*>(bB + phys) = make_uint4(u[0], u[1], u[2], u[3]);
    }
}

// MODE 0: gemm1 (B=Wgu native [H][2I], gate|up 16-col interleave, silu -> bf16)
// MODE 1: gemm2 (B=Wd native [I][H], f32 out)
template<int LDA, int LDB, int NT, int BMG, int BNG, int MODE>
__global__ __launch_bounds__(512, 2) void k_gemm_f(
    const unsigned short* __restrict__ A,
    const float* __restrict__ B,
    void* __restrict__ Cout,
    size_t sA, size_t sB) {
    __shared__ char lds[131072];   // 2 bufs x (A 32K | B 32K)

    const int tid = threadIdx.x, lane = tid & 63, wave = tid >> 6;
    const int wm = wave >> 2, wn = wave & 3;
    const int kg = lane >> 4, r = lane & 15;
    const int rg = tid & 63, kg8 = tid >> 6;   // B-staging role

    // flattened grid, bijective XCD chunking (gridDim.x % 8 == 0), bm innermost
    unsigned flat = blockIdx.x;
    unsigned cpx = gridDim.x >> 3;
    unsigned nid = (flat & 7u) * cpx + (flat >> 3);
    const int bm = nid % BMG;
    const int bn = (nid / BMG) % BNG;
    const int e  = nid / (BMG * BNG);

    const char* gA = (const char*)(A + sA * e) + (size_t)(bm * 256) * LDA;
    size_t colstart;
    if constexpr (MODE == 0)
        colstart = (size_t)(bn * 128 + ((rg >> 4) & 3) * 32 + ((rg >> 2) & 1) * 16
                            + (rg & 3) * 4)
                 + (((rg >> 3) & 1) ? (size_t)I_ : (size_t)0);
    else
        colstart = (size_t)(bn * 256 + rg * 4);
    const char* gBcol = (const char*)B + sB * e + colstart * 4
                      + (size_t)kg8 * 8 * LDB;

    float4 bk[8];

    // ---------------- prologue ----------------
    loadB8<LDB>(gBcol, 0, bk);
    SBAR0;
    asm volatile("s_waitcnt vmcnt(0)" ::: "memory");
    SBAR0;
    cvtWriteB(lds + 32768, bk, rg, kg8);
    SBAR0;
    stageA<LDA>(gA, lds, 0, tid, wave);
    stageA<LDA>(gA, lds, 1, tid, wave);
    stageA<LDA>(gA, lds, 2, tid, wave);
    stageA<LDA>(gA, lds, 3, tid, wave);
    SBAR0;
    loadB8<LDB>(gBcol, 1, bk);
    SBAR0;
    asm volatile("s_waitcnt vmcnt(8)" ::: "memory");   // A(0) done; B(1) in flight
    asm volatile("s_waitcnt lgkmcnt(0)" ::: "memory");
    SBAR0;
    __builtin_amdgcn_s_barrier();
    SBAR0;

    f32x4 acc[8][4] = {};

    for (int t = 0; t < NT; ++t) {
        const char* Ab = lds + (t & 1) * 65536;
        const char* Bb = Ab + 32768;
        char* nA = lds + ((t + 1) & 1) * 65536;
        char* nB = nA + 32768;
        const char* gAn = gA + (size_t)(t + 1) * 128;
        const bool hs1 = (t + 1) < NT, hs2 = (t + 2) < NT;

        bf16x8 af[8], b0[2], bg[2];

        // ---- tile-top staging block (off the MFMA critical path) ----
        if (hs1) {
            asm volatile("s_waitcnt vmcnt(0)" ::: "memory");   // bk = B(t+1) f32 done
            SBAR0;
            cvtWriteB(nB, bk, rg, kg8);
            SBAR0;
            stageA<LDA>(gAn, nA, 0, tid, wave);
            stageA<LDA>(gAn, nA, 1, tid, wave);
            stageA<LDA>(gAn, nA, 2, tid, wave);
            stageA<LDA>(gAn, nA, 3, tid, wave);
            SBAR0;
            if (hs2) { loadB8<LDB>(gBcol, t + 2, bk); SBAR0; }
        }

        // ---- phase 0: kk0, n0-1 ----
        #pragma unroll
        for (int m = 0; m < 8; ++m)
            af[m] = *frag128(Ab, wm * 128 + m * 16 + r, kg * 16);
        #pragma unroll
        for (int n = 0; n < 2; ++n)
            b0[n] = *frag128(Bb, wn * 64 + n * 16 + r, kg * 16);
        asm volatile("s_waitcnt lgkmcnt(0)" ::: "memory");
        SBAR0;
        __builtin_amdgcn_s_setprio(1);
        #pragma unroll
        for (int m = 0; m < 8; ++m) {
            acc[m][0] = MFMA_(af[m], b0[0], acc[m][0], 0, 0, 0);
            acc[m][1] = MFMA_(af[m], b0[1], acc[m][1], 0, 0, 0);
        }
        __builtin_amdgcn_s_setprio(0);
        SBAR0;

        // ---- phase 1: kk0, n2-3 ----
        #pragma unroll
        for (int n = 0; n < 2; ++n)
            bg[n] = *frag128(Bb, wn * 64 + 32 + n * 16 + r, kg * 16);
        asm volatile("s_waitcnt lgkmcnt(0)" ::: "memory");
        SBAR0;
        __builtin_amdgcn_s_setprio(1);
        #pragma unroll
        for (int m = 0; m < 8; ++m) {
            acc[m][2] = MFMA_(af[m], bg[0], acc[m][2], 0, 0, 0);
            acc[m][3] = MFMA_(af[m], bg[1], acc[m][3], 0, 0, 0);
        }
        __builtin_amdgcn_s_setprio(0);
        SBAR0;

        // ---- phase 2: kk1, n0-1 ----
        #pragma unroll
        for (int m = 0; m < 8; ++m)
            af[m] = *frag128(Ab, wm * 128 + m * 16 + r, 64 + kg * 16);
        #pragma unroll
        for (int n = 0; n < 2; ++n)
            b0[n] = *frag128(Bb, wn * 64 + n * 16 + r, 64 + kg * 16);
        asm volatile("s_waitcnt lgkmcnt(0)" ::: "memory");
        SBAR0;
        __builtin_amdgcn_s_setprio(1);
        #pragma unroll
        for (int m = 0; m < 8; ++m) {
            acc[m][0] = MFMA_(af[m], b0[0], acc[m][0], 0, 0, 0);
            acc[m][1] = MFMA_(af[m], b0[1], acc[m][1], 0, 0, 0);
        }
        __builtin_amdgcn_s_setprio(0);
        SBAR0;

        // ---- phase 3: kk1, n2-3 ----
        #pragma unroll
        for (int n = 0; n < 2; ++n)
            bg[n] = *frag128(Bb, wn * 64 + 32 + n * 16 + r, 64 + kg * 16);
        asm volatile("s_waitcnt lgkmcnt(0)" ::: "memory");
        SBAR0;
        __builtin_amdgcn_s_setprio(1);
        #pragma unroll
        for (int m = 0; m < 8; ++m) {
            acc[m][2] = MFMA_(af[m], bg[0], acc[m][2], 0, 0, 0);
            acc[m][3] = MFMA_(af[m], bg[1], acc[m][3], 0, 0, 0);
        }
        __builtin_amdgcn_s_setprio(0);
        SBAR0;

        // ---- boundary: counted drain (A(t+1) done, B(t+2) in flight) ----
        if (hs1) {
            SBAR0;
            if (hs2) asm volatile("s_waitcnt vmcnt(8)" ::: "memory");
            else     asm volatile("s_waitcnt vmcnt(0)" ::: "memory");
            asm volatile("s_waitcnt lgkmcnt(0)" ::: "memory");
            SBAR0;
            __builtin_amdgcn_s_barrier();
            SBAR0;
        }
    }

    // ---------------- epilogue ----------------
    const int row0 = bm * 256 + wm * 128 + kg * 4;   // + m*16 + j
    if constexpr (MODE == 0) {
        unsigned short* act = (unsigned short*)Cout + (size_t)e * C_ * I_;
        const int col0 = bn * 128 + wn * 32 + r;
        #pragma unroll
        for (int m = 0; m < 8; ++m)
            #pragma unroll
            for (int n = 0; n < 2; ++n)
                #pragma unroll
                for (int j = 0; j < 4; ++j) {
                    float g = acc[m][n][j], u = acc[m][n + 2][j];
                    float s = g / (1.0f + __expf(-g)) * u;
                    act[(size_t)(row0 + m * 16 + j) * I_ + col0 + n * 16] = f2bf(s);
                }
    } else {
        float* o = (float*)Cout + (size_t)e * C_ * H_;
        const int col0 = bn * 256 + wn * 64 + r;
        #pragma unroll
        for (int m = 0; m < 8; ++m)
            #pragma unroll
            for (int n = 0; n < 4; ++n)
                #pragma unroll
                for (int j = 0; j < 4; ++j)
                    o[(size_t)(row0 + m * 16 + j) * H_ + col0 + n * 16] = acc[m][n][j];
    }
}

// ---------------- launch ----------------
extern "C" void kernel_launch(void* const* d_in, const int* in_sizes, int n_in,
                              void* d_out, int out_size, void* d_ws, size_t ws_size,
                              hipStream_t stream) {
    const float* hs  = (const float*)d_in[0];   // [E][C][H]
    const float* wgu = (const float*)d_in[1];   // [E][H][2I]
    const float* wd  = (const float*)d_in[2];   // [E][I][H]
    float* out = (float*)d_out;

    char* ws = (char*)d_ws;
    unsigned short* Xbf  = (unsigned short*)(ws);                 // 33,554,432 B
    unsigned short* actb = (unsigned short*)(ws + 33554432ull);   // 67,108,864 B

    k_convert<<<2048, 256, 0, stream>>>(hs, Xbf, E_ * C_ * H_ / 8);

    // GEMM1 (fused transpose+silu): X[EC][H] x Wgu native -> act bf16 [EC][I]
    // BM=256 (BMG=4), 128 act cols/block (BNG=32), NT=32 (BK=64). 1024 blocks.
    k_gemm_f<H_ * 2, N1_ * 4, H_ / 64, 4, 32, 0><<<dim3(1024), 512, 0, stream>>>(
        Xbf, wgu, actb, (size_t)C_ * H_, (size_t)H_ * N1_ * 4);

    // GEMM2 (fused transpose): act[EC][I] x Wd native -> out f32 [EC][H]
    // BM=256 (BMG=4), BN=256 (BNG=8), NT=64 (BK=64). 256 blocks.
    k_gemm_f<I_ * 2, H_ * 4, I_ / 64, 4, 8, 1><<<dim3(256), 512, 0, stream>>>(
        actb, wd, out, (size_t)C_ * I_, (size_t)I_ * H_ * 4);
}